// Round 5
// baseline (2132.722 us; speedup 1.0000x reference)
//
#include <hip/hip_runtime.h>

// GRU-GAN generator, MI355X. Round 5 — R4 + LDS-buffered output flush.
// B=512, H=64, S=2048, F=32.
// 32 blocks x 512 threads; block = 16 batch rows (one M=16 MFMA tile).
// 8 waves: each owns (dir = w>>2, colblock cb = w&3): r,z,n gates via
// v_mfma_f32_16x16x32_bf16; weights in 12 B-fragments (48 VGPR/lane).
// h kept fp32 in registers (C-layout); states cross steps through LDS as
// bf16 A-operand row-major (stride 72 shorts).
// R5 change: y is written to a 16-step LDS ring buffer (ybuf) instead of
// per-step global stores; flushed every 16 steps by all 8 waves with
// coalesced float4 stores. R4 paid ~store-ack latency (600-900cy) at EVERY
// step's barrier (s_waitcnt vmcnt(0) before s_barrier); now 1/16 steps and
// overlapped with the gate-window MFMAs.
// Step pipeline (2 barriers):
//   gates window: [flush every 16] -> gi,gh MFMAs -> gates -> h(t+1) -> LDS
//   barrier1
//   latent window: waves0-3 latent MFMA -> x(t+1) -> Xs, X2s=lk(x)
//                  waves4-5 out-proj of step t-1 from X2s -> ybuf
//   barrier2

#define NBATCH 512
#define NH 64
#define NS 2048
#define NF 32
#define MROW 16
#define LDH 72    // padded LDS row stride (shorts): 144 B
#define YLD 516   // ybuf row stride (dwords): 512 used + 4 pad

typedef short s16x8 __attribute__((ext_vector_type(8)));
typedef float f32x4 __attribute__((ext_vector_type(4)));

#define MFMA(a, b, c) __builtin_amdgcn_mfma_f32_16x16x32_bf16((a), (b), (c), 0, 0, 0)

__device__ __forceinline__ short f2bf(float f) {
    unsigned u = __float_as_uint(f);
    unsigned r = (u + 0x7FFFu + ((u >> 16) & 1u)) >> 16;  // RNE
    return (short)r;
}

__device__ __forceinline__ float lk(float v) { return fmaxf(v, 0.01f * v); }

__device__ __forceinline__ float sigm(float v) {
    float e = __expf(-v);
    return __builtin_amdgcn_rcpf(1.f + e);
}

__device__ __forceinline__ float tanh_fast(float v) {
    // tanh(v) = 1 - 2/(exp(2v)+1); overflow -> inf -> rcp -> 0 -> 1 (correct limit)
    float e = __expf(v + v);
    return 1.f - 2.f * __builtin_amdgcn_rcpf(e + 1.f);
}

// B-fragment for 16x16x32 bf16 MFMA: lane holds B[k = quad*8+j][n = lane&15]
// == 8 consecutive elements of row (n) of row-major W, converted fp32->bf16.
__device__ __forceinline__ s16x8 bfragW(const float* __restrict__ W, int ldk,
                                        int row, int kf, int quad) {
    const float* p = W + (size_t)row * ldk + kf * 32 + quad * 8;
    s16x8 r;
#pragma unroll
    for (int i = 0; i < 8; ++i) r[i] = f2bf(p[i]);
    return r;
}

__global__ __launch_bounds__(512)
void grugan_kernel(const float* __restrict__ noise,
                   const float* __restrict__ Wihf, const float* __restrict__ Whhf,
                   const float* __restrict__ bihf, const float* __restrict__ bhhf,
                   const float* __restrict__ Wihb, const float* __restrict__ Whhb,
                   const float* __restrict__ bihb, const float* __restrict__ bhhb,
                   const float* __restrict__ Wlat, const float* __restrict__ blat,
                   const float* __restrict__ Wout, const float* __restrict__ bout,
                   float* __restrict__ out)
{
    __shared__ __align__(16) short Xs[MROW][LDH];          // x(t), bf16, 1 leaky
    __shared__ __align__(16) short X2s[2][MROW][LDH];      // lk(x(t)), ping-pong
    __shared__ __align__(16) short Hs[2][2][MROW][LDH];    // [t&1][dir][m][k]
    __shared__ __align__(16) float ybuf[MROW][YLD];        // y ring: [row][s*32+f]

    const int tid  = threadIdx.x;
    const int wave = tid >> 6;
    const int lane = tid & 63;
    const int n    = lane & 15;   // tile col (N dim) / A row (M dim)
    const int quad = lane >> 4;
    const int row0 = blockIdx.x * MROW;

    // ---- gate role: all 8 waves ----
    const int dir = wave >> 2;      // 0 fwd, 1 bwd
    const int cb  = wave & 3;       // 16-col block of hidden state
    const int jc  = cb * 16 + n;    // owned hidden col
    const float* Wih = dir ? Wihb : Wihf;
    const float* Whh = dir ? Whhb : Whhf;
    const float* bih = dir ? bihb : bihf;
    const float* bhh = dir ? bhhb : bhhf;

    // 12 weight fragments (48 VGPR) — whole gate weight set for this wave
    s16x8 wir0 = bfragW(Wih, NH,   0 + jc, 0, quad);
    s16x8 wir1 = bfragW(Wih, NH,   0 + jc, 1, quad);
    s16x8 wiz0 = bfragW(Wih, NH,  64 + jc, 0, quad);
    s16x8 wiz1 = bfragW(Wih, NH,  64 + jc, 1, quad);
    s16x8 win0 = bfragW(Wih, NH, 128 + jc, 0, quad);
    s16x8 win1 = bfragW(Wih, NH, 128 + jc, 1, quad);
    s16x8 whr0 = bfragW(Whh, NH,   0 + jc, 0, quad);
    s16x8 whr1 = bfragW(Whh, NH,   0 + jc, 1, quad);
    s16x8 whz0 = bfragW(Whh, NH,  64 + jc, 0, quad);
    s16x8 whz1 = bfragW(Whh, NH,  64 + jc, 1, quad);
    s16x8 whn0 = bfragW(Whh, NH, 128 + jc, 0, quad);
    s16x8 whn1 = bfragW(Whh, NH, 128 + jc, 1, quad);
    const float brz_r = bih[jc]       + bhh[jc];
    const float brz_z = bih[64 + jc]  + bhh[64 + jc];
    const float bin   = bih[128 + jc];
    const float bhn   = bhh[128 + jc];

    // ---- latent role (waves 0-3); safe-indexed loads for all waves ----
    const int n0 = (wave & 3) * 16;
    s16x8 wl0 = bfragW(Wlat, 2 * NH, n0 + n, 0, quad);
    s16x8 wl1 = bfragW(Wlat, 2 * NH, n0 + n, 1, quad);
    s16x8 wl2 = bfragW(Wlat, 2 * NH, n0 + n, 2, quad);
    s16x8 wl3 = bfragW(Wlat, 2 * NH, n0 + n, 3, quad);
    const float bl = blat[n0 + n];

    // ---- out-proj role (waves 4,5); safe-indexed loads for all waves ----
    const int f0 = (wave & 1) * 16;
    s16x8 wo0 = bfragW(Wout, NH, f0 + n, 0, quad);
    s16x8 wo1 = bfragW(Wout, NH, f0 + n, 1, quad);
    const float bo = bout[f0 + n];

    // ---- state init: x0 = 0; h = noise (fp32 in regs, bf16 copy in Hs[0]) ----
    for (int idx = tid; idx < MROW * LDH; idx += 512) (&Xs[0][0])[idx] = 0;
    float hreg[4];
#pragma unroll
    for (int i = 0; i < 4; ++i) {
        hreg[i] = noise[(size_t)(row0 + quad * 4 + i) * NH + jc];
        Hs[0][dir][quad * 4 + i][jc] = f2bf(hreg[i]);
    }
    __syncthreads();

    for (int t = 0; t < NS; ++t) {
        const int hb = t & 1;
        // ---------------- gates window ----------------
        // flush y(t-17..t-2) every 16 steps; coalesced, all 8 waves;
        // store latency overlaps the MFMA work below, drain amortized 16x
        if ((t & 15) == 1 && t >= 17) {
            const int tbase = t - 17;
#pragma unroll
            for (int rr = 0; rr < 2; ++rr) {
                const int r = wave * 2 + rr;
                const float4* src = (const float4*)&ybuf[r][0];
                float4* dst = (float4*)(out + (size_t)(row0 + r) * (NS * NF)
                                            + (size_t)tbase * NF);
                dst[lane]      = src[lane];
                dst[lane + 64] = src[lane + 64];
            }
        }
        // A-frags: rows m = lane&15
        s16x8 xa0 = *(const s16x8*)&Xs[n][quad * 8];
        s16x8 xa1 = *(const s16x8*)&Xs[n][32 + quad * 8];
        s16x8 ha0 = *(const s16x8*)&Hs[hb][dir][n][quad * 8];
        s16x8 ha1 = *(const s16x8*)&Hs[hb][dir][n][32 + quad * 8];
        f32x4 gr = {0.f, 0.f, 0.f, 0.f}, gz = gr, gn = gr;
        f32x4 hr = gr, hz = gr, hn = gr;
        gr = MFMA(xa0, wir0, gr); gr = MFMA(xa1, wir1, gr);
        gz = MFMA(xa0, wiz0, gz); gz = MFMA(xa1, wiz1, gz);
        gn = MFMA(xa0, win0, gn); gn = MFMA(xa1, win1, gn);
        hr = MFMA(ha0, whr0, hr); hr = MFMA(ha1, whr1, hr);
        hz = MFMA(ha0, whz0, hz); hz = MFMA(ha1, whz1, hz);
        hn = MFMA(ha0, whn0, hn); hn = MFMA(ha1, whn1, hn);
        // gates + h update; C layout: row = quad*4+i, col = jc
#pragma unroll
        for (int i = 0; i < 4; ++i) {
            float r  = sigm(gr[i] + hr[i] + brz_r);
            float z  = sigm(gz[i] + hz[i] + brz_z);
            float nn = tanh_fast(gn[i] + bin + r * (hn[i] + bhn));
            float hv = nn + z * (hreg[i] - nn);   // (1-z)n + z h
            hreg[i] = hv;
            Hs[hb ^ 1][dir][quad * 4 + i][jc] = f2bf(hv);
        }
        __syncthreads();   // barrier1: H(t+1) visible
        // ---------------- latent window ----------------
        if (wave < 4) {
            s16x8 fa0 = *(const s16x8*)&Hs[hb ^ 1][0][n][quad * 8];
            s16x8 fa1 = *(const s16x8*)&Hs[hb ^ 1][0][n][32 + quad * 8];
            s16x8 ba0 = *(const s16x8*)&Hs[hb ^ 1][1][n][quad * 8];
            s16x8 ba1 = *(const s16x8*)&Hs[hb ^ 1][1][n][32 + quad * 8];
            f32x4 ac0 = {0.f, 0.f, 0.f, 0.f}, ac1 = ac0;
            ac0 = MFMA(fa0, wl0, ac0); ac0 = MFMA(fa1, wl1, ac0);
            ac1 = MFMA(ba0, wl2, ac1); ac1 = MFMA(ba1, wl3, ac1);
#pragma unroll
            for (int i = 0; i < 4; ++i) {
                float la = lk(ac0[i] + ac1[i] + bl);   // ys[t] = x(t+1)
                Xs[quad * 4 + i][n0 + n]          = f2bf(la);
                X2s[hb ^ 1][quad * 4 + i][n0 + n] = f2bf(lk(la));
            }
        } else if (wave < 6 && t >= 1) {
            // out-proj for step t-1: input lk(x(t)) = X2s[t&1]; y -> ybuf ring
            s16x8 p0 = *(const s16x8*)&X2s[hb][n][quad * 8];
            s16x8 p1 = *(const s16x8*)&X2s[hb][n][32 + quad * 8];
            f32x4 po = {0.f, 0.f, 0.f, 0.f};
            po = MFMA(p0, wo0, po); po = MFMA(p1, wo1, po);
            const int ys_ = (t - 1) & 15;
#pragma unroll
            for (int i = 0; i < 4; ++i)
                ybuf[quad * 4 + i][ys_ * 32 + f0 + n] = sigm(po[i] + bo);
        }
        __syncthreads();   // barrier2: x(t+1) visible
    }

    // ---------------- epilogue ----------------
    // y(2047) from X2s[NS&1 = 0], into ybuf slot 15; then flush y(2032..2047)
    if (wave == 4 || wave == 5) {
        s16x8 p0 = *(const s16x8*)&X2s[0][n][quad * 8];
        s16x8 p1 = *(const s16x8*)&X2s[0][n][32 + quad * 8];
        f32x4 po = {0.f, 0.f, 0.f, 0.f};
        po = MFMA(p0, wo0, po); po = MFMA(p1, wo1, po);
#pragma unroll
        for (int i = 0; i < 4; ++i)
            ybuf[quad * 4 + i][15 * 32 + f0 + n] = sigm(po[i] + bo);
    }
    __syncthreads();
    {
        const int tbase = NS - 16;
#pragma unroll
        for (int rr = 0; rr < 2; ++rr) {
            const int r = wave * 2 + rr;
            const float4* src = (const float4*)&ybuf[r][0];
            float4* dst = (float4*)(out + (size_t)(row0 + r) * (NS * NF)
                                        + (size_t)tbase * NF);
            dst[lane]      = src[lane];
            dst[lane + 64] = src[lane + 64];
        }
    }
}

extern "C" void kernel_launch(void* const* d_in, const int* in_sizes, int n_in,
                              void* d_out, int out_size, void* d_ws, size_t ws_size,
                              hipStream_t stream) {
    const float* noise = (const float*)d_in[0];
    const float* Wihf  = (const float*)d_in[1];
    const float* Whhf  = (const float*)d_in[2];
    const float* bihf  = (const float*)d_in[3];
    const float* bhhf  = (const float*)d_in[4];
    const float* Wihb  = (const float*)d_in[5];
    const float* Whhb  = (const float*)d_in[6];
    const float* bihb  = (const float*)d_in[7];
    const float* bhhb  = (const float*)d_in[8];
    const float* Wlat  = (const float*)d_in[9];
    const float* blat  = (const float*)d_in[10];
    const float* Wout  = (const float*)d_in[11];
    const float* bout  = (const float*)d_in[12];

    grugan_kernel<<<dim3(NBATCH / MROW), dim3(512), 0, stream>>>(
        noise, Wihf, Whhf, bihf, bhhf, Wihb, Whhb, bihb, bhhb,
        Wlat, blat, Wout, bout, (float*)d_out);
}

// Round 6
// 1742.824 us; speedup vs baseline: 1.2237x; 1.2237x over previous
//
#include <hip/hip_runtime.h>

// GRU-GAN generator, MI355X. Round 6 — balanced two-window MFMA pipeline.
// B=512, H=64, S=2048, F=32.
// 32 blocks x 512 threads; block = 16 batch rows (one M=16 MFMA tile).
// 8 waves; roles: gates (all 8: dir=w>>2, colblock=w&3), latent (waves 0-3),
// out-proj (waves 6,7). Weights resident as MFMA B-fragments.
// R6 restructure vs R4/R5 (which were VALU-issue + latency-chain bound,
// ~2300 cy/step):
//  * gh MFMAs (h(t+1)·Whh^T) moved into the latent window — run concurrently
//    with latent/out-proj, carried across barrier2 in VGPR accumulators.
//    Gates window: only 6 gi MFMAs + gate elementwise.
//  * biases folded into MFMA accumulator init (loop-invariant f32x4 splats).
//  * f2bf cheapened to round-nearest-ties-away (2 insts vs 5).
//  * direct per-step y stores (R4 style; R5's LDS ring regressed).
// Step pipeline (2 barriers):
//   gates:  [store y(t-2)] -> 6 gi MFMA (onto carried gh+bias accs) ->
//           gates+h-update -> Hs[hb^1]
//   barrier1
//   latent: all: read ha(h(t+1)), 6 gh MFMA for t+1 (bias-init accs)
//           w0-3: + latent MFMA -> x(t+1)=lk(lat) -> Xs[hb^1], X2s[hb^1]=lk(x)
//           w6-7: + out-proj of ys[t-1] from X2s[hb] -> yv regs
//   barrier2

#define NBATCH 512
#define NH 64
#define NS 2048
#define NF 32
#define MROW 16
#define LDH 72    // padded LDS row stride (shorts): 144 B

typedef short s16x8 __attribute__((ext_vector_type(8)));
typedef float f32x4 __attribute__((ext_vector_type(4)));

#define MFMA(a, b, c) __builtin_amdgcn_mfma_f32_16x16x32_bf16((a), (b), (c), 0, 0, 0)

__device__ __forceinline__ short f2bf(float f) {
    // round-to-nearest (ties away): 2 VALU insts
    return (short)((__float_as_uint(f) + 0x8000u) >> 16);
}

__device__ __forceinline__ float lk(float v) { return fmaxf(v, 0.01f * v); }

__device__ __forceinline__ float sigm(float v) {
    float e = __expf(-v);
    return __builtin_amdgcn_rcpf(1.f + e);
}

__device__ __forceinline__ float tanh_fast(float v) {
    // tanh(v) = 1 - 2/(exp(2v)+1); overflow -> inf -> rcp -> 0 -> 1
    float e = __expf(v + v);
    return 1.f - 2.f * __builtin_amdgcn_rcpf(e + 1.f);
}

// B-fragment for 16x16x32 bf16 MFMA: lane holds B[k = quad*8+j][n = lane&15]
// == 8 consecutive elements of row n of row-major W, converted fp32->bf16.
__device__ __forceinline__ s16x8 bfragW(const float* __restrict__ W, int ldk,
                                        int row, int kf, int quad) {
    const float* p = W + (size_t)row * ldk + kf * 32 + quad * 8;
    s16x8 r;
#pragma unroll
    for (int i = 0; i < 8; ++i) r[i] = f2bf(p[i]);
    return r;
}

__global__ __launch_bounds__(512)
void grugan_kernel(const float* __restrict__ noise,
                   const float* __restrict__ Wihf, const float* __restrict__ Whhf,
                   const float* __restrict__ bihf, const float* __restrict__ bhhf,
                   const float* __restrict__ Wihb, const float* __restrict__ Whhb,
                   const float* __restrict__ bihb, const float* __restrict__ bhhb,
                   const float* __restrict__ Wlat, const float* __restrict__ blat,
                   const float* __restrict__ Wout, const float* __restrict__ bout,
                   float* __restrict__ out)
{
    __shared__ __align__(16) short Xs[2][MROW][LDH];       // x(t) bf16 (1 leaky), ping-pong
    __shared__ __align__(16) short X2s[2][MROW][LDH];      // lk(x(t)), ping-pong
    __shared__ __align__(16) short Hs[2][2][MROW][LDH];    // [t&1][dir][m][k]

    const int tid  = threadIdx.x;
    const int wave = tid >> 6;
    const int lane = tid & 63;
    const int n    = lane & 15;   // tile col (N) / A-frag row (M)
    const int quad = lane >> 4;
    const int row0 = blockIdx.x * MROW;

    // ---- gate role (all 8 waves) ----
    const int dir = wave >> 2;      // 0 fwd, 1 bwd
    const int cb  = wave & 3;       // 16-col block
    const int jc  = cb * 16 + n;    // owned hidden col
    const float* Wih = dir ? Wihb : Wihf;
    const float* Whh = dir ? Whhb : Whhf;
    const float* bih = dir ? bihb : bihf;
    const float* bhh = dir ? bhhb : bhhf;

    s16x8 wir0 = bfragW(Wih, NH,   0 + jc, 0, quad);
    s16x8 wir1 = bfragW(Wih, NH,   0 + jc, 1, quad);
    s16x8 wiz0 = bfragW(Wih, NH,  64 + jc, 0, quad);
    s16x8 wiz1 = bfragW(Wih, NH,  64 + jc, 1, quad);
    s16x8 win0 = bfragW(Wih, NH, 128 + jc, 0, quad);
    s16x8 win1 = bfragW(Wih, NH, 128 + jc, 1, quad);
    s16x8 whr0 = bfragW(Whh, NH,   0 + jc, 0, quad);
    s16x8 whr1 = bfragW(Whh, NH,   0 + jc, 1, quad);
    s16x8 whz0 = bfragW(Whh, NH,  64 + jc, 0, quad);
    s16x8 whz1 = bfragW(Whh, NH,  64 + jc, 1, quad);
    s16x8 whn0 = bfragW(Whh, NH, 128 + jc, 0, quad);
    s16x8 whn1 = bfragW(Whh, NH, 128 + jc, 1, quad);
    const float brz_r = bih[jc]      + bhh[jc];
    const float brz_z = bih[64 + jc] + bhh[64 + jc];
    const float bin   = bih[128 + jc];
    const float bhn   = bhh[128 + jc];
    const f32x4 initR  = {brz_r, brz_r, brz_r, brz_r};
    const f32x4 initZ  = {brz_z, brz_z, brz_z, brz_z};
    const f32x4 initN1 = {bin, bin, bin, bin};
    const f32x4 initN2 = {bhn, bhn, bhn, bhn};

    // ---- latent role (waves 0-3); indices safe for all waves ----
    const int n0 = (wave & 3) * 16;
    s16x8 wl0 = bfragW(Wlat, 2 * NH, n0 + n, 0, quad);
    s16x8 wl1 = bfragW(Wlat, 2 * NH, n0 + n, 1, quad);
    s16x8 wl2 = bfragW(Wlat, 2 * NH, n0 + n, 2, quad);
    s16x8 wl3 = bfragW(Wlat, 2 * NH, n0 + n, 3, quad);
    const float bl = blat[n0 + n];
    const f32x4 initL = {bl, bl, bl, bl};

    // ---- out-proj role (waves 6,7); indices safe for all waves ----
    const int f0 = (wave & 1) * 16;
    s16x8 wo0 = bfragW(Wout, NH, f0 + n, 0, quad);
    s16x8 wo1 = bfragW(Wout, NH, f0 + n, 1, quad);
    const float bo = bout[f0 + n];
    const f32x4 initO = {bo, bo, bo, bo};

    // ---- state init: x0 = 0 -> Xs[0]; h(0) = noise -> hreg + Hs[0] ----
    for (int idx = tid; idx < MROW * LDH; idx += 512) (&Xs[0][0][0])[idx] = 0;
    float hreg[4];
#pragma unroll
    for (int i = 0; i < 4; ++i) {
        hreg[i] = noise[(size_t)(row0 + quad * 4 + i) * NH + jc];
        Hs[0][dir][quad * 4 + i][jc] = f2bf(hreg[i]);
    }
    __syncthreads();

    // ---- prologue: gh accumulators for t=0 from h(0) ----
    f32x4 accR, accZ, accN2;
    {
        s16x8 ha0 = *(const s16x8*)&Hs[0][dir][n][quad * 8];
        s16x8 ha1 = *(const s16x8*)&Hs[0][dir][n][32 + quad * 8];
        accR  = MFMA(ha0, whr0, initR);  accR  = MFMA(ha1, whr1, accR);
        accZ  = MFMA(ha0, whz0, initZ);  accZ  = MFMA(ha1, whz1, accZ);
        accN2 = MFMA(ha0, whn0, initN2); accN2 = MFMA(ha1, whn1, accN2);
    }

    f32x4 yv = {0.f, 0.f, 0.f, 0.f};   // pending y row (waves 6,7)

    for (int t = 0; t < NS; ++t) {
        const int hb = t & 1;
        // ---------------- gates window ----------------
        if (t >= 2 && wave >= 6) {
            const size_t tb = (size_t)(t - 2) * NF + f0 + n;
#pragma unroll
            for (int i = 0; i < 4; ++i)
                out[(size_t)(row0 + quad * 4 + i) * (NS * NF) + tb] = yv[i];
        }
        s16x8 xa0 = *(const s16x8*)&Xs[hb][n][quad * 8];
        s16x8 xa1 = *(const s16x8*)&Xs[hb][n][32 + quad * 8];
        accR = MFMA(xa0, wir0, accR);   accR = MFMA(xa1, wir1, accR);
        accZ = MFMA(xa0, wiz0, accZ);   accZ = MFMA(xa1, wiz1, accZ);
        f32x4 accN1 = MFMA(xa0, win0, initN1);
        accN1 = MFMA(xa1, win1, accN1);
        // gates + h update; C layout: row = quad*4+i, col = jc
#pragma unroll
        for (int i = 0; i < 4; ++i) {
            float r  = sigm(accR[i]);
            float z  = sigm(accZ[i]);
            float nn = tanh_fast(fmaf(r, accN2[i], accN1[i]));
            float hv = nn + z * (hreg[i] - nn);   // (1-z)n + z h
            hreg[i] = hv;
            Hs[hb ^ 1][dir][quad * 4 + i][jc] = f2bf(hv);
        }
        __syncthreads();   // barrier1: H(t+1) visible
        // ---------------- latent window ----------------
        // all waves: gh accumulators for step t+1 (own dir)
        s16x8 ha0 = *(const s16x8*)&Hs[hb ^ 1][dir][n][quad * 8];
        s16x8 ha1 = *(const s16x8*)&Hs[hb ^ 1][dir][n][32 + quad * 8];
        accR  = MFMA(ha0, whr0, initR);  accR  = MFMA(ha1, whr1, accR);
        accZ  = MFMA(ha0, whz0, initZ);  accZ  = MFMA(ha1, whz1, accZ);
        accN2 = MFMA(ha0, whn0, initN2); accN2 = MFMA(ha1, whn1, accN2);
        if (wave < 4) {
            // latent: k 0..63 = fwd h (== ha frags, dir=0), k 64..127 = bwd h
            s16x8 ba0 = *(const s16x8*)&Hs[hb ^ 1][1][n][quad * 8];
            s16x8 ba1 = *(const s16x8*)&Hs[hb ^ 1][1][n][32 + quad * 8];
            f32x4 lac = MFMA(ha0, wl0, initL);
            lac = MFMA(ha1, wl1, lac);
            lac = MFMA(ba0, wl2, lac);
            lac = MFMA(ba1, wl3, lac);
#pragma unroll
            for (int i = 0; i < 4; ++i) {
                float la = lk(lac[i]);   // ys[t] = x(t+1)
                Xs[hb ^ 1][quad * 4 + i][n0 + n]  = f2bf(la);
                X2s[hb ^ 1][quad * 4 + i][n0 + n] = f2bf(lk(la));
            }
        } else if (wave >= 6 && t >= 1) {
            // out-proj of ys[t-1]: input lk(x(t)) = X2s[hb]
            s16x8 p0 = *(const s16x8*)&X2s[hb][n][quad * 8];
            s16x8 p1 = *(const s16x8*)&X2s[hb][n][32 + quad * 8];
            f32x4 po = MFMA(p0, wo0, initO);
            po = MFMA(p1, wo1, po);
#pragma unroll
            for (int i = 0; i < 4; ++i) yv[i] = sigm(po[i]);
        }
        __syncthreads();   // barrier2: x(t+1) visible
    }

    // ---------------- epilogue (waves 6,7) ----------------
    if (wave >= 6) {
        // store ys row 2046 (computed in latent window t=2047)
        {
            const size_t tb = (size_t)(NS - 2) * NF + f0 + n;
#pragma unroll
            for (int i = 0; i < 4; ++i)
                out[(size_t)(row0 + quad * 4 + i) * (NS * NF) + tb] = yv[i];
        }
        // ys row 2047 from X2s[(NS)&1 = 0] (written latent t=2047)
        s16x8 p0 = *(const s16x8*)&X2s[0][n][quad * 8];
        s16x8 p1 = *(const s16x8*)&X2s[0][n][32 + quad * 8];
        f32x4 po = MFMA(p0, wo0, initO);
        po = MFMA(p1, wo1, po);
        const size_t tb = (size_t)(NS - 1) * NF + f0 + n;
#pragma unroll
        for (int i = 0; i < 4; ++i)
            out[(size_t)(row0 + quad * 4 + i) * (NS * NF) + tb] = sigm(po[i]);
    }
}

extern "C" void kernel_launch(void* const* d_in, const int* in_sizes, int n_in,
                              void* d_out, int out_size, void* d_ws, size_t ws_size,
                              hipStream_t stream) {
    const float* noise = (const float*)d_in[0];
    const float* Wihf  = (const float*)d_in[1];
    const float* Whhf  = (const float*)d_in[2];
    const float* bihf  = (const float*)d_in[3];
    const float* bhhf  = (const float*)d_in[4];
    const float* Wihb  = (const float*)d_in[5];
    const float* Whhb  = (const float*)d_in[6];
    const float* bihb  = (const float*)d_in[7];
    const float* bhhb  = (const float*)d_in[8];
    const float* Wlat  = (const float*)d_in[9];
    const float* blat  = (const float*)d_in[10];
    const float* Wout  = (const float*)d_in[11];
    const float* bout  = (const float*)d_in[12];

    grugan_kernel<<<dim3(NBATCH / MROW), dim3(512), 0, stream>>>(
        noise, Wihf, Whhf, bihf, bhhf, Wihb, Whhb, bihb, bhhb,
        Wlat, blat, Wout, bout, (float*)d_out);
}

// Round 7
// 1676.766 us; speedup vs baseline: 1.2719x; 1.0394x over previous
//
#include <hip/hip_runtime.h>

// GRU-GAN generator, MI355X. Round 7 — transposed MFMA (operand swap) + packed LDS writes.
// B=512, H=64, S=2048, F=32.
// 32 blocks x 512 threads; block = 16 batch rows. 8 waves: gates (all 8,
// dir=w>>2, colblock=w&3), latent (w0-3), out-proj (w6-7).
// R7 key change: MFMA(W, x, C) instead of MFMA(x, W, C) — for 16x16 MFMA the
// A/B fragment layouts are identical, so swapping operands transposes D:
// lane now holds 4 CONSECUTIVE gate-cols (j = quad*4+i) of ONE batch row
// (m = lane&15). This turns the per-step LDS state writes from 4x ds_write_b16
// (144B stride scatter) into 1x packed ds_write_b64, and y stores into one
// float4 (R6 was LDS-pipe co-bound: ~64 b16 writes + 44 b128 reads ~ 850cy/CU/step).
// Also: t-loop unrolled by 2 (compile-time ping-pong -> static LDS addressing),
// biases/noise as float4 loads, waves_per_eu(2,2) to protect ~140 VGPR.
// Step pipeline (2 barriers), roles as R6 (gh carried across barrier2 in regs).

#define NBATCH 512
#define NH 64
#define NS 2048
#define NF 32
#define MROW 16
#define LDH 72    // padded LDS row stride (shorts): 144 B

typedef short s16x4 __attribute__((ext_vector_type(4)));
typedef short s16x8 __attribute__((ext_vector_type(8)));
typedef float f32x4 __attribute__((ext_vector_type(4)));

#define MFMA(a, b, c) __builtin_amdgcn_mfma_f32_16x16x32_bf16((a), (b), (c), 0, 0, 0)

__device__ __forceinline__ short f2bf(float f) {
    return (short)((__float_as_uint(f) + 0x8000u) >> 16);  // RN ties-away
}

__device__ __forceinline__ float lk(float v) { return fmaxf(v, 0.01f * v); }

__device__ __forceinline__ float sigm(float v) {
    float e = __expf(-v);
    return __builtin_amdgcn_rcpf(1.f + e);
}

__device__ __forceinline__ float tanh_fast(float v) {
    // tanh(v) = 1 - 2/(exp(2v)+1); overflow -> inf -> rcp -> 0 -> 1
    float e = __expf(v + v);
    return 1.f - 2.f * __builtin_amdgcn_rcpf(e + 1.f);
}

// Weight fragment: lane holds 8 consecutive elements of row `row` of row-major
// W (fp32 -> bf16). Same bits serve as A-operand (row index = lane&15) here.
__device__ __forceinline__ s16x8 bfragW(const float* __restrict__ W, int ldk,
                                        int row, int kf, int quad) {
    const float* p = W + (size_t)row * ldk + kf * 32 + quad * 8;
    s16x8 r;
#pragma unroll
    for (int i = 0; i < 8; ++i) r[i] = f2bf(p[i]);
    return r;
}

__device__ __forceinline__ f32x4 bias4(const float* __restrict__ p) {
    const float4 v = *(const float4*)p;
    f32x4 r = {v.x, v.y, v.z, v.w};
    return r;
}

__global__ __launch_bounds__(512)
__attribute__((amdgpu_waves_per_eu(2, 2)))
void grugan_kernel(const float* __restrict__ noise,
                   const float* __restrict__ Wihf, const float* __restrict__ Whhf,
                   const float* __restrict__ bihf, const float* __restrict__ bhhf,
                   const float* __restrict__ Wihb, const float* __restrict__ Whhb,
                   const float* __restrict__ bihb, const float* __restrict__ bhhb,
                   const float* __restrict__ Wlat, const float* __restrict__ blat,
                   const float* __restrict__ Wout, const float* __restrict__ bout,
                   float* __restrict__ out)
{
    __shared__ __align__(16) short Xs[2][MROW][LDH];       // x(t) bf16, ping-pong
    __shared__ __align__(16) short X2s[2][MROW][LDH];      // lk(x(t)), ping-pong
    __shared__ __align__(16) short Hs[2][2][MROW][LDH];    // [t&1][dir][m][k]

    const int tid  = threadIdx.x;
    const int wave = tid >> 6;
    const int lane = tid & 63;
    const int n    = lane & 15;   // batch row within tile (D col after swap)
    const int quad = lane >> 4;
    const int row0 = blockIdx.x * MROW;

    // ---- gate role (all 8 waves) ----
    const int dir  = wave >> 2;          // 0 fwd, 1 bwd
    const int cb   = wave & 3;           // 16-col block of hidden state
    const int jrow = cb * 16 + n;        // weight row (W-frag A-side index)
    const int jq   = cb * 16 + quad * 4; // this lane's 4 owned k-cols
    const float* Wih = dir ? Wihb : Wihf;
    const float* Whh = dir ? Whhb : Whhf;
    const float* bih = dir ? bihb : bihf;
    const float* bhh = dir ? bhhb : bhhf;

    s16x8 wir0 = bfragW(Wih, NH,   0 + jrow, 0, quad);
    s16x8 wir1 = bfragW(Wih, NH,   0 + jrow, 1, quad);
    s16x8 wiz0 = bfragW(Wih, NH,  64 + jrow, 0, quad);
    s16x8 wiz1 = bfragW(Wih, NH,  64 + jrow, 1, quad);
    s16x8 win0 = bfragW(Wih, NH, 128 + jrow, 0, quad);
    s16x8 win1 = bfragW(Wih, NH, 128 + jrow, 1, quad);
    s16x8 whr0 = bfragW(Whh, NH,   0 + jrow, 0, quad);
    s16x8 whr1 = bfragW(Whh, NH,   0 + jrow, 1, quad);
    s16x8 whz0 = bfragW(Whh, NH,  64 + jrow, 0, quad);
    s16x8 whz1 = bfragW(Whh, NH,  64 + jrow, 1, quad);
    s16x8 whn0 = bfragW(Whh, NH, 128 + jrow, 0, quad);
    s16x8 whn1 = bfragW(Whh, NH, 128 + jrow, 1, quad);
    // per-component biases (lane owns 4 consecutive j's)
    f32x4 initR, initZ;
    {
        f32x4 a = bias4(&bih[jq]),      b = bias4(&bhh[jq]);
        initR = a + b;
        f32x4 c = bias4(&bih[64 + jq]), d = bias4(&bhh[64 + jq]);
        initZ = c + d;
    }
    const f32x4 initN1 = bias4(&bih[128 + jq]);
    const f32x4 initN2 = bias4(&bhh[128 + jq]);

    // ---- latent role (waves 0-3); safe indices for all waves ----
    const int nq = (wave & 3) * 16 + quad * 4;   // lane's 4 latent cols
    s16x8 wl0 = bfragW(Wlat, 2 * NH, (wave & 3) * 16 + n, 0, quad);
    s16x8 wl1 = bfragW(Wlat, 2 * NH, (wave & 3) * 16 + n, 1, quad);
    s16x8 wl2 = bfragW(Wlat, 2 * NH, (wave & 3) * 16 + n, 2, quad);
    s16x8 wl3 = bfragW(Wlat, 2 * NH, (wave & 3) * 16 + n, 3, quad);
    const f32x4 initL = bias4(&blat[(wave & 3) * 16 + quad * 4]);

    // ---- out-proj role (waves 6,7); safe indices for all waves ----
    const int f0 = (wave & 1) * 16;
    s16x8 wo0 = bfragW(Wout, NH, f0 + n, 0, quad);
    s16x8 wo1 = bfragW(Wout, NH, f0 + n, 1, quad);
    const f32x4 initO = bias4(&bout[f0 + quad * 4]);
    float* const orow = out + (size_t)(row0 + n) * (NS * NF) + f0 + quad * 4;

    // ---- state init: x0 = 0 -> Xs[0]; h(0) = noise -> hreg + Hs[0] ----
    for (int idx = tid; idx < MROW * LDH; idx += 512) (&Xs[0][0][0])[idx] = 0;
    f32x4 hreg;
    {
        const float4 nz = *(const float4*)&noise[(size_t)(row0 + n) * NH + jq];
        hreg[0] = nz.x; hreg[1] = nz.y; hreg[2] = nz.z; hreg[3] = nz.w;
        s16x4 hp = {f2bf(nz.x), f2bf(nz.y), f2bf(nz.z), f2bf(nz.w)};
        *(s16x4*)&Hs[0][dir][n][jq] = hp;
    }
    __syncthreads();

    // ---- prologue: gh accumulators for t=0 from h(0) ----
    f32x4 accR, accZ, accN2;
    {
        s16x8 ha0 = *(const s16x8*)&Hs[0][dir][n][quad * 8];
        s16x8 ha1 = *(const s16x8*)&Hs[0][dir][n][32 + quad * 8];
        accR  = MFMA(whr0, ha0, initR);  accR  = MFMA(whr1, ha1, accR);
        accZ  = MFMA(whz0, ha0, initZ);  accZ  = MFMA(whz1, ha1, accZ);
        accN2 = MFMA(whn0, ha0, initN2); accN2 = MFMA(whn1, ha1, accN2);
    }

    f32x4 yv = {0.f, 0.f, 0.f, 0.f};   // pending y (waves 6,7): 4 f's of row n

#define STEP(HB, T) do {                                                        \
    if ((T) >= 2 && wave >= 6)                                                  \
        *(f32x4*)(orow + (size_t)((T) - 2) * NF) = yv;                          \
    {                                                                           \
        s16x8 xa0 = *(const s16x8*)&Xs[HB][n][quad * 8];                        \
        s16x8 xa1 = *(const s16x8*)&Xs[HB][n][32 + quad * 8];                   \
        accR = MFMA(wir0, xa0, accR);   accR = MFMA(wir1, xa1, accR);           \
        accZ = MFMA(wiz0, xa0, accZ);   accZ = MFMA(wiz1, xa1, accZ);           \
        f32x4 accN1 = MFMA(win0, xa0, initN1);                                  \
        accN1 = MFMA(win1, xa1, accN1);                                         \
        s16x4 hp;                                                               \
        _Pragma("unroll")                                                       \
        for (int i = 0; i < 4; ++i) {                                           \
            float r  = sigm(accR[i]);                                           \
            float z  = sigm(accZ[i]);                                           \
            float nn = tanh_fast(fmaf(r, accN2[i], accN1[i]));                  \
            float hv = nn + z * (hreg[i] - nn);                                 \
            hreg[i] = hv;                                                       \
            hp[i] = f2bf(hv);                                                   \
        }                                                                       \
        *(s16x4*)&Hs[(HB) ^ 1][dir][n][jq] = hp;                                \
    }                                                                           \
    __syncthreads();  /* barrier1: H(t+1) visible */                            \
    {                                                                           \
        s16x8 ha0 = *(const s16x8*)&Hs[(HB) ^ 1][dir][n][quad * 8];             \
        s16x8 ha1 = *(const s16x8*)&Hs[(HB) ^ 1][dir][n][32 + quad * 8];        \
        accR  = MFMA(whr0, ha0, initR);  accR  = MFMA(whr1, ha1, accR);         \
        accZ  = MFMA(whz0, ha0, initZ);  accZ  = MFMA(whz1, ha1, accZ);         \
        accN2 = MFMA(whn0, ha0, initN2); accN2 = MFMA(whn1, ha1, accN2);        \
        if (wave < 4) {                                                         \
            s16x8 ba0 = *(const s16x8*)&Hs[(HB) ^ 1][1][n][quad * 8];           \
            s16x8 ba1 = *(const s16x8*)&Hs[(HB) ^ 1][1][n][32 + quad * 8];      \
            f32x4 lac = MFMA(wl0, ha0, initL);                                  \
            lac = MFMA(wl1, ha1, lac);                                          \
            lac = MFMA(wl2, ba0, lac);                                          \
            lac = MFMA(wl3, ba1, lac);                                          \
            s16x4 xp, x2p;                                                      \
            _Pragma("unroll")                                                   \
            for (int i = 0; i < 4; ++i) {                                       \
                float la = lk(lac[i]);                                          \
                xp[i]  = f2bf(la);                                              \
                x2p[i] = f2bf(lk(la));                                          \
            }                                                                   \
            *(s16x4*)&Xs[(HB) ^ 1][n][nq]  = xp;                                \
            *(s16x4*)&X2s[(HB) ^ 1][n][nq] = x2p;                               \
        } else if (wave >= 6 && (T) >= 1) {                                     \
            s16x8 p0 = *(const s16x8*)&X2s[HB][n][quad * 8];                    \
            s16x8 p1 = *(const s16x8*)&X2s[HB][n][32 + quad * 8];               \
            f32x4 po = MFMA(wo0, p0, initO);                                    \
            po = MFMA(wo1, p1, po);                                             \
            _Pragma("unroll")                                                   \
            for (int i = 0; i < 4; ++i) yv[i] = sigm(po[i]);                    \
        }                                                                       \
    }                                                                           \
    __syncthreads();  /* barrier2: x(t+1) visible */                            \
} while (0)

    for (int t = 0; t < NS; t += 2) {
        STEP(0, t);
        STEP(1, t + 1);
    }
#undef STEP

    // ---------------- epilogue (waves 6,7) ----------------
    if (wave >= 6) {
        *(f32x4*)(orow + (size_t)(NS - 2) * NF) = yv;   // ys[2046]
        s16x8 p0 = *(const s16x8*)&X2s[0][n][quad * 8]; // lk(x(2047)) in X2s[0]
        s16x8 p1 = *(const s16x8*)&X2s[0][n][32 + quad * 8];
        f32x4 po = MFMA(wo0, p0, initO);
        po = MFMA(wo1, p1, po);
        f32x4 yf;
#pragma unroll
        for (int i = 0; i < 4; ++i) yf[i] = sigm(po[i]);
        *(f32x4*)(orow + (size_t)(NS - 1) * NF) = yf;   // ys[2047]
    }
}

extern "C" void kernel_launch(void* const* d_in, const int* in_sizes, int n_in,
                              void* d_out, int out_size, void* d_ws, size_t ws_size,
                              hipStream_t stream) {
    const float* noise = (const float*)d_in[0];
    const float* Wihf  = (const float*)d_in[1];
    const float* Whhf  = (const float*)d_in[2];
    const float* bihf  = (const float*)d_in[3];
    const float* bhhf  = (const float*)d_in[4];
    const float* Wihb  = (const float*)d_in[5];
    const float* Whhb  = (const float*)d_in[6];
    const float* bihb  = (const float*)d_in[7];
    const float* bhhb  = (const float*)d_in[8];
    const float* Wlat  = (const float*)d_in[9];
    const float* blat  = (const float*)d_in[10];
    const float* Wout  = (const float*)d_in[11];
    const float* bout  = (const float*)d_in[12];

    grugan_kernel<<<dim3(NBATCH / MROW), dim3(512), 0, stream>>>(
        noise, Wihf, Whhf, bihf, bhhf, Wihb, Whhb, bihb, bhhb,
        Wlat, blat, Wout, bout, (float*)d_out);
}

// Round 8
// 1625.833 us; speedup vs baseline: 1.3118x; 1.0313x over previous
//
#include <hip/hip_runtime.h>
#include <hip/hip_bf16.h>

// GRU-GAN generator, MI355X. Round 8 — merged-rcp gate math + pk-vectorized elementwise.
// B=512, H=64, S=2048, F=32. 32 blocks x 512 threads; block = 16 batch rows.
// 8 waves: gates (all 8, dir=w>>2, colblock=w&3), latent (w0-3), out-proj (w6-7).
// Structure as R7 (transposed MFMA D[j][m], packed b64 LDS state writes, unroll-2).
// R8 changes (R7 measured ~1020 cy/step/SIMD VALU issue, ~half transcendentals):
//  * exact merged-rcp GRU update: h' = [e_z(1-e_u)+h(1+e_u)]/[(1+e_u)(1+e_z)],
//    e_z=exp(-b_z), e_u=exp(-2u), u = accN1 + r*accN2, r = 1/(1+exp(-b_r)).
//    One rcp instead of three (5 trans/elem vs 6), fewer blend ops.
//  * all non-trans elementwise written as f32x4 vector ops (v_pk_*_f32 chance).
//  * f32->bf16 via __float22bfloat162_rn (v_cvt_pk_bf16_f32: 1 inst / 2 vals).
//  * W2 reordered: latent MFMA + Xs/X2s stores BEFORE the 6 gh MFMAs (gh only
//    needed after barrier2) — shortens the barrier2 critical path.

#define NBATCH 512
#define NH 64
#define NS 2048
#define NF 32
#define MROW 16
#define LDH 72    // padded LDS row stride (shorts): 144 B

typedef short s16x4 __attribute__((ext_vector_type(4)));
typedef short s16x8 __attribute__((ext_vector_type(8)));
typedef float f32x4 __attribute__((ext_vector_type(4)));

#define MFMA(a, b, c) __builtin_amdgcn_mfma_f32_16x16x32_bf16((a), (b), (c), 0, 0, 0)

#define NLOG2E  (-1.4426950408889634f)   // -log2(e)
#define N2LOG2E (-2.8853900817779268f)   // -2*log2(e)

__device__ __forceinline__ short f2bf(float f) {
    return (short)((__float_as_uint(f) + 0x8000u) >> 16);
}

__device__ __forceinline__ f32x4 v_exp2(f32x4 a) {
    f32x4 r;
#pragma unroll
    for (int i = 0; i < 4; ++i) r[i] = __builtin_amdgcn_exp2f(a[i]);
    return r;
}

__device__ __forceinline__ f32x4 v_rcp(f32x4 a) {
    f32x4 r;
#pragma unroll
    for (int i = 0; i < 4; ++i) r[i] = __builtin_amdgcn_rcpf(a[i]);
    return r;
}

__device__ __forceinline__ f32x4 v_lk(f32x4 a) {
    f32x4 b = a * 0.01f;
    f32x4 r;
#pragma unroll
    for (int i = 0; i < 4; ++i) r[i] = fmaxf(a[i], b[i]);
    return r;
}

// vector sigmoid: 1/(1+exp(-x))
__device__ __forceinline__ f32x4 v_sigm(f32x4 a) {
    return v_rcp(v_exp2(a * NLOG2E) + 1.0f);
}

// pack 4 fp32 -> 4 bf16 (RNE) as int2 via v_cvt_pk_bf16_f32
__device__ __forceinline__ int2 pk4bf(f32x4 v) {
    union { __hip_bfloat162 b; int i; } lo, hi;
    float2 a; a.x = v[0]; a.y = v[1];
    float2 b; b.x = v[2]; b.y = v[3];
    lo.b = __float22bfloat162_rn(a);
    hi.b = __float22bfloat162_rn(b);
    int2 r; r.x = lo.i; r.y = hi.i;
    return r;
}

__device__ __forceinline__ s16x8 bfragW(const float* __restrict__ W, int ldk,
                                        int row, int kf, int quad) {
    const float* p = W + (size_t)row * ldk + kf * 32 + quad * 8;
    s16x8 r;
#pragma unroll
    for (int i = 0; i < 8; ++i) r[i] = f2bf(p[i]);
    return r;
}

__device__ __forceinline__ f32x4 bias4(const float* __restrict__ p) {
    const float4 v = *(const float4*)p;
    f32x4 r = {v.x, v.y, v.z, v.w};
    return r;
}

__global__ __launch_bounds__(512)
__attribute__((amdgpu_waves_per_eu(2, 2)))
void grugan_kernel(const float* __restrict__ noise,
                   const float* __restrict__ Wihf, const float* __restrict__ Whhf,
                   const float* __restrict__ bihf, const float* __restrict__ bhhf,
                   const float* __restrict__ Wihb, const float* __restrict__ Whhb,
                   const float* __restrict__ bihb, const float* __restrict__ bhhb,
                   const float* __restrict__ Wlat, const float* __restrict__ blat,
                   const float* __restrict__ Wout, const float* __restrict__ bout,
                   float* __restrict__ out)
{
    __shared__ __align__(16) short Xs[2][MROW][LDH];
    __shared__ __align__(16) short X2s[2][MROW][LDH];
    __shared__ __align__(16) short Hs[2][2][MROW][LDH];

    const int tid  = threadIdx.x;
    const int wave = tid >> 6;
    const int lane = tid & 63;
    const int n    = lane & 15;
    const int quad = lane >> 4;
    const int row0 = blockIdx.x * MROW;

    const int dir  = wave >> 2;
    const int cb   = wave & 3;
    const int jrow = cb * 16 + n;
    const int jq   = cb * 16 + quad * 4;
    const float* Wih = dir ? Wihb : Wihf;
    const float* Whh = dir ? Whhb : Whhf;
    const float* bih = dir ? bihb : bihf;
    const float* bhh = dir ? bhhb : bhhf;

    s16x8 wir0 = bfragW(Wih, NH,   0 + jrow, 0, quad);
    s16x8 wir1 = bfragW(Wih, NH,   0 + jrow, 1, quad);
    s16x8 wiz0 = bfragW(Wih, NH,  64 + jrow, 0, quad);
    s16x8 wiz1 = bfragW(Wih, NH,  64 + jrow, 1, quad);
    s16x8 win0 = bfragW(Wih, NH, 128 + jrow, 0, quad);
    s16x8 win1 = bfragW(Wih, NH, 128 + jrow, 1, quad);
    s16x8 whr0 = bfragW(Whh, NH,   0 + jrow, 0, quad);
    s16x8 whr1 = bfragW(Whh, NH,   0 + jrow, 1, quad);
    s16x8 whz0 = bfragW(Whh, NH,  64 + jrow, 0, quad);
    s16x8 whz1 = bfragW(Whh, NH,  64 + jrow, 1, quad);
    s16x8 whn0 = bfragW(Whh, NH, 128 + jrow, 0, quad);
    s16x8 whn1 = bfragW(Whh, NH, 128 + jrow, 1, quad);
    f32x4 initR, initZ;
    {
        f32x4 a = bias4(&bih[jq]),      b = bias4(&bhh[jq]);
        initR = a + b;
        f32x4 c = bias4(&bih[64 + jq]), d = bias4(&bhh[64 + jq]);
        initZ = c + d;
    }
    const f32x4 initN1 = bias4(&bih[128 + jq]);
    const f32x4 initN2 = bias4(&bhh[128 + jq]);

    const int nq = (wave & 3) * 16 + quad * 4;
    s16x8 wl0 = bfragW(Wlat, 2 * NH, (wave & 3) * 16 + n, 0, quad);
    s16x8 wl1 = bfragW(Wlat, 2 * NH, (wave & 3) * 16 + n, 1, quad);
    s16x8 wl2 = bfragW(Wlat, 2 * NH, (wave & 3) * 16 + n, 2, quad);
    s16x8 wl3 = bfragW(Wlat, 2 * NH, (wave & 3) * 16 + n, 3, quad);
    const f32x4 initL = bias4(&blat[(wave & 3) * 16 + quad * 4]);

    const int f0 = (wave & 1) * 16;
    s16x8 wo0 = bfragW(Wout, NH, f0 + n, 0, quad);
    s16x8 wo1 = bfragW(Wout, NH, f0 + n, 1, quad);
    const f32x4 initO = bias4(&bout[f0 + quad * 4]);
    float* const orow = out + (size_t)(row0 + n) * (NS * NF) + f0 + quad * 4;

    for (int idx = tid; idx < MROW * LDH; idx += 512) (&Xs[0][0][0])[idx] = 0;
    f32x4 hreg;
    {
        const float4 nz = *(const float4*)&noise[(size_t)(row0 + n) * NH + jq];
        hreg[0] = nz.x; hreg[1] = nz.y; hreg[2] = nz.z; hreg[3] = nz.w;
        *(int2*)&Hs[0][dir][n][jq] = pk4bf(hreg);
    }
    __syncthreads();

    f32x4 accR, accZ, accN2;
    {
        s16x8 ha0 = *(const s16x8*)&Hs[0][dir][n][quad * 8];
        s16x8 ha1 = *(const s16x8*)&Hs[0][dir][n][32 + quad * 8];
        accR  = MFMA(whr0, ha0, initR);  accR  = MFMA(whr1, ha1, accR);
        accZ  = MFMA(whz0, ha0, initZ);  accZ  = MFMA(whz1, ha1, accZ);
        accN2 = MFMA(whn0, ha0, initN2); accN2 = MFMA(whn1, ha1, accN2);
    }

    f32x4 yv = {0.f, 0.f, 0.f, 0.f};

#define STEP(HB, T) do {                                                        \
    if ((T) >= 2 && wave >= 6)                                                  \
        *(f32x4*)(orow + (size_t)((T) - 2) * NF) = yv;                          \
    {                                                                           \
        s16x8 xa0 = *(const s16x8*)&Xs[HB][n][quad * 8];                        \
        s16x8 xa1 = *(const s16x8*)&Xs[HB][n][32 + quad * 8];                   \
        accR = MFMA(wir0, xa0, accR);   accR = MFMA(wir1, xa1, accR);           \
        accZ = MFMA(wiz0, xa0, accZ);   accZ = MFMA(wiz1, xa1, accZ);           \
        f32x4 accN1 = MFMA(win0, xa0, initN1);                                  \
        accN1 = MFMA(win1, xa1, accN1);                                         \
        /* merged-rcp GRU update (exact):                                    */ \
        /* r = 1/(1+eR); u = N1 + r*N2; eU = exp(-2u); eZ = exp(-accZ);      */ \
        /* h' = [(eZ+h) + eU*(h-eZ)] / [(1+eU)(1+eZ)]                        */ \
        f32x4 eR = v_exp2(accR * NLOG2E);                                       \
        f32x4 rr = v_rcp(eR + 1.0f);                                            \
        f32x4 u  = accN1 + rr * accN2;                                          \
        f32x4 eU = v_exp2(u * N2LOG2E);                                         \
        f32x4 eZ = v_exp2(accZ * NLOG2E);                                       \
        f32x4 numer = (eZ + hreg) + eU * (hreg - eZ);                           \
        f32x4 denom = (eU + 1.0f) * (eZ + 1.0f);                                \
        hreg = numer * v_rcp(denom);                                            \
        *(int2*)&Hs[(HB) ^ 1][dir][n][jq] = pk4bf(hreg);                        \
    }                                                                           \
    __syncthreads();  /* barrier1: H(t+1) visible */                            \
    {                                                                           \
        s16x8 ha0 = *(const s16x8*)&Hs[(HB) ^ 1][dir][n][quad * 8];             \
        s16x8 ha1 = *(const s16x8*)&Hs[(HB) ^ 1][dir][n][32 + quad * 8];        \
        if (wave < 4) {                                                         \
            /* latent first: its stores gate barrier2 */                        \
            s16x8 ba0 = *(const s16x8*)&Hs[(HB) ^ 1][1][n][quad * 8];           \
            s16x8 ba1 = *(const s16x8*)&Hs[(HB) ^ 1][1][n][32 + quad * 8];      \
            f32x4 lac = MFMA(wl0, ha0, initL);                                  \
            lac = MFMA(wl1, ha1, lac);                                          \
            lac = MFMA(wl2, ba0, lac);                                          \
            lac = MFMA(wl3, ba1, lac);                                          \
            f32x4 la = v_lk(lac);                                               \
            *(int2*)&Xs[(HB) ^ 1][n][nq]  = pk4bf(la);                          \
            *(int2*)&X2s[(HB) ^ 1][n][nq] = pk4bf(v_lk(la));                    \
        } else if (wave >= 6 && (T) >= 1) {                                     \
            s16x8 p0 = *(const s16x8*)&X2s[HB][n][quad * 8];                    \
            s16x8 p1 = *(const s16x8*)&X2s[HB][n][32 + quad * 8];               \
            f32x4 po = MFMA(wo0, p0, initO);                                    \
            po = MFMA(wo1, p1, po);                                             \
            yv = v_sigm(po);                                                    \
        }                                                                       \
        /* gh for next step: results consumed only after barrier2 */            \
        accR  = MFMA(whr0, ha0, initR);  accR  = MFMA(whr1, ha1, accR);         \
        accZ  = MFMA(whz0, ha0, initZ);  accZ  = MFMA(whz1, ha1, accZ);         \
        accN2 = MFMA(whn0, ha0, initN2); accN2 = MFMA(whn1, ha1, accN2);        \
    }                                                                           \
    __syncthreads();  /* barrier2: x(t+1) visible */                            \
} while (0)

    for (int t = 0; t < NS; t += 2) {
        STEP(0, t);
        STEP(1, t + 1);
    }
#undef STEP

    if (wave >= 6) {
        *(f32x4*)(orow + (size_t)(NS - 2) * NF) = yv;
        s16x8 p0 = *(const s16x8*)&X2s[0][n][quad * 8];
        s16x8 p1 = *(const s16x8*)&X2s[0][n][32 + quad * 8];
        f32x4 po = MFMA(wo0, p0, initO);
        po = MFMA(wo1, p1, po);
        *(f32x4*)(orow + (size_t)(NS - 1) * NF) = v_sigm(po);
    }
}

extern "C" void kernel_launch(void* const* d_in, const int* in_sizes, int n_in,
                              void* d_out, int out_size, void* d_ws, size_t ws_size,
                              hipStream_t stream) {
    const float* noise = (const float*)d_in[0];
    const float* Wihf  = (const float*)d_in[1];
    const float* Whhf  = (const float*)d_in[2];
    const float* bihf  = (const float*)d_in[3];
    const float* bhhf  = (const float*)d_in[4];
    const float* Wihb  = (const float*)d_in[5];
    const float* Whhb  = (const float*)d_in[6];
    const float* bihb  = (const float*)d_in[7];
    const float* bhhb  = (const float*)d_in[8];
    const float* Wlat  = (const float*)d_in[9];
    const float* blat  = (const float*)d_in[10];
    const float* Wout  = (const float*)d_in[11];
    const float* bout  = (const float*)d_in[12];

    grugan_kernel<<<dim3(NBATCH / MROW), dim3(512), 0, stream>>>(
        noise, Wihf, Whhf, bihf, bhhf, Wihb, Whhb, bihb, bhhb,
        Wlat, blat, Wout, bout, (float*)d_out);
}

// Round 9
// 1613.303 us; speedup vs baseline: 1.3220x; 1.0078x over previous
//
#include <hip/hip_runtime.h>
#include <hip/hip_bf16.h>

// GRU-GAN generator, MI355X. Round 9 — full wave-role specialization.
// B=512, H=64, S=2048, F=32. 32 blocks x 1024 threads (16 waves, 4/SIMD).
// Block = 16 batch rows (one M=16 MFMA tile, transposed D[j][m] layout).
//   waves 0-7 : gates (dir=w>>2, cb=w&3). W1: x-read, 6 gi MFMA, merged-rcp
//               GRU elementwise, packed h write. W2: 6 gh MFMA (carried regs).
//   waves 8-11: latent. W2 only: h(t+1) read (both dirs), 4 MFMA, leaky,
//               packed Xs/X2s writes. No W1 work -> their W2 chain starts
//               at barrier1 with zero lead-in (R8's latent was serialized
//               behind the same wave's gate tail; ~800cy/step stall term).
//   waves 12-13: out-proj. W1: y(t-2) float4 store; W2: X2s read, 2 MFMA, sigm.
//   waves 14-15: barrier-matched idle.
// All paths: exactly 2 __syncthreads per step, same order (legal divergent
// wave-uniform barriers, counts matched).
// Numerics: exact merged-rcp GRU update (R8), bf16 state via v_cvt_pk_bf16_f32.

#define NBATCH 512
#define NH 64
#define NS 2048
#define NF 32
#define MROW 16
#define LDH 72    // padded LDS row stride (shorts): 144 B

typedef short s16x8 __attribute__((ext_vector_type(8)));
typedef float f32x4 __attribute__((ext_vector_type(4)));

#define MFMA(a, b, c) __builtin_amdgcn_mfma_f32_16x16x32_bf16((a), (b), (c), 0, 0, 0)

#define NLOG2E  (-1.4426950408889634f)   // -log2(e)
#define N2LOG2E (-2.8853900817779268f)   // -2*log2(e)

__device__ __forceinline__ short f2bf(float f) {
    return (short)((__float_as_uint(f) + 0x8000u) >> 16);
}

__device__ __forceinline__ f32x4 v_exp2(f32x4 a) {
    f32x4 r;
#pragma unroll
    for (int i = 0; i < 4; ++i) r[i] = __builtin_amdgcn_exp2f(a[i]);
    return r;
}

__device__ __forceinline__ f32x4 v_rcp(f32x4 a) {
    f32x4 r;
#pragma unroll
    for (int i = 0; i < 4; ++i) r[i] = __builtin_amdgcn_rcpf(a[i]);
    return r;
}

__device__ __forceinline__ f32x4 v_lk(f32x4 a) {
    f32x4 b = a * 0.01f;
    f32x4 r;
#pragma unroll
    for (int i = 0; i < 4; ++i) r[i] = fmaxf(a[i], b[i]);
    return r;
}

__device__ __forceinline__ f32x4 v_sigm(f32x4 a) {
    return v_rcp(v_exp2(a * NLOG2E) + 1.0f);
}

__device__ __forceinline__ int2 pk4bf(f32x4 v) {
    union { __hip_bfloat162 b; int i; } lo, hi;
    float2 a; a.x = v[0]; a.y = v[1];
    float2 b; b.x = v[2]; b.y = v[3];
    lo.b = __float22bfloat162_rn(a);
    hi.b = __float22bfloat162_rn(b);
    int2 r; r.x = lo.i; r.y = hi.i;
    return r;
}

__device__ __forceinline__ s16x8 bfragW(const float* __restrict__ W, int ldk,
                                        int row, int kf, int quad) {
    const float* p = W + (size_t)row * ldk + kf * 32 + quad * 8;
    s16x8 r;
#pragma unroll
    for (int i = 0; i < 8; ++i) r[i] = f2bf(p[i]);
    return r;
}

__device__ __forceinline__ f32x4 bias4(const float* __restrict__ p) {
    const float4 v = *(const float4*)p;
    f32x4 r = {v.x, v.y, v.z, v.w};
    return r;
}

__global__ __launch_bounds__(1024)
void grugan_kernel(const float* __restrict__ noise,
                   const float* __restrict__ Wihf, const float* __restrict__ Whhf,
                   const float* __restrict__ bihf, const float* __restrict__ bhhf,
                   const float* __restrict__ Wihb, const float* __restrict__ Whhb,
                   const float* __restrict__ bihb, const float* __restrict__ bhhb,
                   const float* __restrict__ Wlat, const float* __restrict__ blat,
                   const float* __restrict__ Wout, const float* __restrict__ bout,
                   float* __restrict__ out)
{
    __shared__ __align__(16) short Xs[2][MROW][LDH];
    __shared__ __align__(16) short X2s[2][MROW][LDH];
    __shared__ __align__(16) short Hs[2][2][MROW][LDH];

    const int tid  = threadIdx.x;
    const int wave = tid >> 6;
    const int lane = tid & 63;
    const int n    = lane & 15;   // batch row within tile
    const int quad = lane >> 4;
    const int row0 = blockIdx.x * MROW;

    // zero x(0); init h(0) (gate waves hold hreg; both dirs covered)
    for (int idx = tid; idx < MROW * LDH; idx += 1024) (&Xs[0][0][0])[idx] = 0;
    f32x4 hreg = {0.f, 0.f, 0.f, 0.f};
    const int gdir = wave >> 2;             // valid for waves 0-7
    const int gjq  = (wave & 3) * 16 + quad * 4;
    if (wave < 8) {
        const float4 nz = *(const float4*)&noise[(size_t)(row0 + n) * NH + gjq];
        hreg[0] = nz.x; hreg[1] = nz.y; hreg[2] = nz.z; hreg[3] = nz.w;
        *(int2*)&Hs[0][gdir][n][gjq] = pk4bf(hreg);
    }
    __syncthreads();

    if (wave < 8) {
        // ======================= GATE WAVES =======================
        const int dir  = gdir;
        const int cb   = wave & 3;
        const int jrow = cb * 16 + n;
        const int jq   = gjq;
        const float* Wih = dir ? Wihb : Wihf;
        const float* Whh = dir ? Whhb : Whhf;
        const float* bih = dir ? bihb : bihf;
        const float* bhh = dir ? bhhb : bhhf;

        s16x8 wir0 = bfragW(Wih, NH,   0 + jrow, 0, quad);
        s16x8 wir1 = bfragW(Wih, NH,   0 + jrow, 1, quad);
        s16x8 wiz0 = bfragW(Wih, NH,  64 + jrow, 0, quad);
        s16x8 wiz1 = bfragW(Wih, NH,  64 + jrow, 1, quad);
        s16x8 win0 = bfragW(Wih, NH, 128 + jrow, 0, quad);
        s16x8 win1 = bfragW(Wih, NH, 128 + jrow, 1, quad);
        s16x8 whr0 = bfragW(Whh, NH,   0 + jrow, 0, quad);
        s16x8 whr1 = bfragW(Whh, NH,   0 + jrow, 1, quad);
        s16x8 whz0 = bfragW(Whh, NH,  64 + jrow, 0, quad);
        s16x8 whz1 = bfragW(Whh, NH,  64 + jrow, 1, quad);
        s16x8 whn0 = bfragW(Whh, NH, 128 + jrow, 0, quad);
        s16x8 whn1 = bfragW(Whh, NH, 128 + jrow, 1, quad);
        f32x4 initR, initZ;
        {
            f32x4 a = bias4(&bih[jq]),      b = bias4(&bhh[jq]);
            initR = a + b;
            f32x4 c = bias4(&bih[64 + jq]), d = bias4(&bhh[64 + jq]);
            initZ = c + d;
        }
        const f32x4 initN1 = bias4(&bih[128 + jq]);
        const f32x4 initN2 = bias4(&bhh[128 + jq]);

        // prologue: gh accumulators for t=0 from h(0)
        f32x4 accR, accZ, accN2;
        {
            s16x8 ha0 = *(const s16x8*)&Hs[0][dir][n][quad * 8];
            s16x8 ha1 = *(const s16x8*)&Hs[0][dir][n][32 + quad * 8];
            accR  = MFMA(whr0, ha0, initR);  accR  = MFMA(whr1, ha1, accR);
            accZ  = MFMA(whz0, ha0, initZ);  accZ  = MFMA(whz1, ha1, accZ);
            accN2 = MFMA(whn0, ha0, initN2); accN2 = MFMA(whn1, ha1, accN2);
        }

#define GSTEP(HB) do {                                                          \
        s16x8 xa0 = *(const s16x8*)&Xs[HB][n][quad * 8];                        \
        s16x8 xa1 = *(const s16x8*)&Xs[HB][n][32 + quad * 8];                   \
        accR = MFMA(wir0, xa0, accR);   accR = MFMA(wir1, xa1, accR);           \
        accZ = MFMA(wiz0, xa0, accZ);   accZ = MFMA(wiz1, xa1, accZ);           \
        f32x4 accN1 = MFMA(win0, xa0, initN1);                                  \
        accN1 = MFMA(win1, xa1, accN1);                                         \
        f32x4 eR = v_exp2(accR * NLOG2E);                                       \
        f32x4 rr = v_rcp(eR + 1.0f);                                            \
        f32x4 u  = accN1 + rr * accN2;                                          \
        f32x4 eU = v_exp2(u * N2LOG2E);                                         \
        f32x4 eZ = v_exp2(accZ * NLOG2E);                                       \
        f32x4 numer = (eZ + hreg) + eU * (hreg - eZ);                           \
        f32x4 denom = (eU + 1.0f) * (eZ + 1.0f);                                \
        hreg = numer * v_rcp(denom);                                            \
        *(int2*)&Hs[(HB) ^ 1][dir][n][jq] = pk4bf(hreg);                        \
        __syncthreads();  /* b1: H(t+1) visible */                              \
        {                                                                       \
            s16x8 ha0 = *(const s16x8*)&Hs[(HB) ^ 1][dir][n][quad * 8];         \
            s16x8 ha1 = *(const s16x8*)&Hs[(HB) ^ 1][dir][n][32 + quad * 8];    \
            accR  = MFMA(whr0, ha0, initR);  accR  = MFMA(whr1, ha1, accR);     \
            accZ  = MFMA(whz0, ha0, initZ);  accZ  = MFMA(whz1, ha1, accZ);     \
            accN2 = MFMA(whn0, ha0, initN2); accN2 = MFMA(whn1, ha1, accN2);    \
        }                                                                       \
        __syncthreads();  /* b2: x(t+1) visible */                              \
    } while (0)

        for (int t = 0; t < NS; t += 2) {
            GSTEP(0);
            GSTEP(1);
        }
#undef GSTEP
    } else if (wave < 12) {
        // ======================= LATENT WAVES =======================
        const int lt = wave & 3;
        const int nq = lt * 16 + quad * 4;
        s16x8 wl0 = bfragW(Wlat, 2 * NH, lt * 16 + n, 0, quad);
        s16x8 wl1 = bfragW(Wlat, 2 * NH, lt * 16 + n, 1, quad);
        s16x8 wl2 = bfragW(Wlat, 2 * NH, lt * 16 + n, 2, quad);
        s16x8 wl3 = bfragW(Wlat, 2 * NH, lt * 16 + n, 3, quad);
        const f32x4 initL = bias4(&blat[lt * 16 + quad * 4]);

#define LSTEP(HB) do {                                                          \
        __syncthreads();  /* b1: H(t+1) visible */                              \
        s16x8 fa0 = *(const s16x8*)&Hs[(HB) ^ 1][0][n][quad * 8];               \
        s16x8 fa1 = *(const s16x8*)&Hs[(HB) ^ 1][0][n][32 + quad * 8];          \
        s16x8 ba0 = *(const s16x8*)&Hs[(HB) ^ 1][1][n][quad * 8];               \
        s16x8 ba1 = *(const s16x8*)&Hs[(HB) ^ 1][1][n][32 + quad * 8];          \
        f32x4 lac = MFMA(wl0, fa0, initL);                                      \
        lac = MFMA(wl1, fa1, lac);                                              \
        lac = MFMA(wl2, ba0, lac);                                              \
        lac = MFMA(wl3, ba1, lac);                                              \
        f32x4 la = v_lk(lac);                                                   \
        *(int2*)&Xs[(HB) ^ 1][n][nq]  = pk4bf(la);                              \
        *(int2*)&X2s[(HB) ^ 1][n][nq] = pk4bf(v_lk(la));                        \
        __syncthreads();  /* b2: x(t+1) visible */                              \
    } while (0)

        for (int t = 0; t < NS; t += 2) {
            LSTEP(0);
            LSTEP(1);
        }
#undef LSTEP
    } else if (wave < 14) {
        // ======================= OUT-PROJ WAVES =======================
        const int f0 = (wave & 1) * 16;
        s16x8 wo0 = bfragW(Wout, NH, f0 + n, 0, quad);
        s16x8 wo1 = bfragW(Wout, NH, f0 + n, 1, quad);
        const f32x4 initO = bias4(&bout[f0 + quad * 4]);
        float* const orow = out + (size_t)(row0 + n) * (NS * NF) + f0 + quad * 4;
        f32x4 yv = {0.f, 0.f, 0.f, 0.f};

#define OSTEP(HB, T) do {                                                       \
        if ((T) >= 2)                                                           \
            *(f32x4*)(orow + (size_t)((T) - 2) * NF) = yv;                      \
        __syncthreads();  /* b1 */                                              \
        if ((T) >= 1) {                                                         \
            s16x8 p0 = *(const s16x8*)&X2s[HB][n][quad * 8];                    \
            s16x8 p1 = *(const s16x8*)&X2s[HB][n][32 + quad * 8];               \
            f32x4 po = MFMA(wo0, p0, initO);                                    \
            po = MFMA(wo1, p1, po);                                             \
            yv = v_sigm(po);                                                    \
        }                                                                       \
        __syncthreads();  /* b2 */                                              \
    } while (0)

        for (int t = 0; t < NS; t += 2) {
            OSTEP(0, t);
            OSTEP(1, t + 1);
        }
#undef OSTEP

        // epilogue: y(NS-2) pending in yv; y(NS-1) from X2s[0] (= lk(x(NS)))
        *(f32x4*)(orow + (size_t)(NS - 2) * NF) = yv;
        s16x8 p0 = *(const s16x8*)&X2s[0][n][quad * 8];
        s16x8 p1 = *(const s16x8*)&X2s[0][n][32 + quad * 8];
        f32x4 po = MFMA(wo0, p0, initO);
        po = MFMA(wo1, p1, po);
        *(f32x4*)(orow + (size_t)(NS - 1) * NF) = v_sigm(po);
    } else {
        // ======================= IDLE WAVES (barrier-matched) ==========
#pragma unroll 1
        for (int i = 0; i < 2 * NS; ++i) __syncthreads();
    }
}

extern "C" void kernel_launch(void* const* d_in, const int* in_sizes, int n_in,
                              void* d_out, int out_size, void* d_ws, size_t ws_size,
                              hipStream_t stream) {
    const float* noise = (const float*)d_in[0];
    const float* Wihf  = (const float*)d_in[1];
    const float* Whhf  = (const float*)d_in[2];
    const float* bihf  = (const float*)d_in[3];
    const float* bhhf  = (const float*)d_in[4];
    const float* Wihb  = (const float*)d_in[5];
    const float* Whhb  = (const float*)d_in[6];
    const float* bihb  = (const float*)d_in[7];
    const float* bhhb  = (const float*)d_in[8];
    const float* Wlat  = (const float*)d_in[9];
    const float* blat  = (const float*)d_in[10];
    const float* Wout  = (const float*)d_in[11];
    const float* bout  = (const float*)d_in[12];

    grugan_kernel<<<dim3(NBATCH / MROW), dim3(1024), 0, stream>>>(
        noise, Wihf, Whhf, bihf, bhhf, Wihb, Whhb, bihb, bhhb,
        Wlat, blat, Wout, bout, (float*)d_out);
}